// Round 1
// baseline (147.814 us; speedup 1.0000x reference)
//
#include <hip/hip_runtime.h>

#define PP 10
#define LL 6
#define NIMG 4
#define HW (1024*1024)
#define BINS 66  // 60 inter bins (l*10+p) + 6 label-count bins

__global__ void zero_ws_kernel(float* ws, int n) {
    int i = blockIdx.x * blockDim.x + threadIdx.x;
    if (i < n) ws[i] = 0.0f;
}

__global__ __launch_bounds__(256) void accum_kernel(
    const float* __restrict__ pred,
    const int*   __restrict__ pconn,
    const int*   __restrict__ lconn,
    float*       __restrict__ ws)
{
    const int img = blockIdx.y;
    const size_t base = (size_t)img * HW;
    const int wave = threadIdx.x >> 6;
    __shared__ float s_bins[4][BINS];

    for (int i = threadIdx.x; i < 4 * BINS; i += blockDim.x)
        ((float*)s_bins)[i] = 0.0f;
    __syncthreads();

    const float4* p4  = (const float4*)(pred  + base);
    const int4*   pc4 = (const int4*)(pconn + base);
    const int4*   lc4 = (const int4*)(lconn + base);
    const int nvec = HW / 4;
    const int stride = gridDim.x * blockDim.x;
    float* bins = s_bins[wave];

    for (int v = blockIdx.x * blockDim.x + threadIdx.x; v < nvec; v += stride) {
        float4 p  = p4[v];
        int4   pc = pc4[v];
        int4   lc = lc4[v];
        atomicAdd(&bins[lc.x * PP + pc.x], p.x);
        atomicAdd(&bins[lc.y * PP + pc.y], p.y);
        atomicAdd(&bins[lc.z * PP + pc.z], p.z);
        atomicAdd(&bins[lc.w * PP + pc.w], p.w);
        atomicAdd(&bins[60 + lc.x], 1.0f);
        atomicAdd(&bins[60 + lc.y], 1.0f);
        atomicAdd(&bins[60 + lc.z], 1.0f);
        atomicAdd(&bins[60 + lc.w], 1.0f);
    }
    __syncthreads();

    if (threadIdx.x < BINS) {
        float s = s_bins[0][threadIdx.x] + s_bins[1][threadIdx.x]
                + s_bins[2][threadIdx.x] + s_bins[3][threadIdx.x];
        atomicAdd(&ws[img * BINS + threadIdx.x], s);
    }
}

__global__ void finalize_kernel(const float* __restrict__ ws, float* __restrict__ out) {
    if (threadIdx.x != 0 || blockIdx.x != 0) return;
    float total = 0.0f;
    for (int img = 0; img < NIMG; ++img) {
        const float* b = ws + img * BINS;
        float inter[LL][PP];
        float pred_area[PP];
        float label_area[LL];
        for (int p = 0; p < PP; ++p) pred_area[p] = 0.0f;
        for (int l = 0; l < LL; ++l) {
            label_area[l] = b[60 + l];
            for (int p = 0; p < PP; ++p) {
                inter[l][p] = b[l * PP + p];
                pred_area[p] += inter[l][p];
            }
        }
        // ious = iou[1:,1:]
        float ious[LL][PP];
        for (int l = 1; l < LL; ++l) {
            for (int p = 1; p < PP; ++p) {
                float in = inter[l][p];
                float un = label_area[l] + pred_area[p] - in;
                float iou;
                if (in == 0.0f)      iou = 0.0f;
                else if (un == 0.0f) iou = 1.0f;
                else                 iou = in / un;
                ious[l][p] = iou;
            }
        }
        float pair_conn_sum = 0.0f;
        for (int l = 1; l < LL; ++l) {
            float pc = 0.0f; int pn = 0;
            for (int p = 1; p < PP; ++p) {
                pc += ious[l][p];
                pn += (ious[l][p] != 0.0f) ? 1 : 0;
            }
            if (pn > 0) pair_conn_sum += pc / (float)pn;
        }
        int lone = 0;
        for (int p = 1; p < PP; ++p) {
            float cs = 0.0f;
            for (int l = 1; l < LL; ++l) cs += ious[l][p];
            lone += (cs == 0.0f) ? 1 : 0;
        }
        float img_conn = pair_conn_sum / (5.0f + (float)lone);
        total += 1.0f - img_conn;
    }
    out[0] = total / (float)NIMG;
}

extern "C" void kernel_launch(void* const* d_in, const int* in_sizes, int n_in,
                              void* d_out, int out_size, void* d_ws, size_t ws_size,
                              hipStream_t stream) {
    const float* pred  = (const float*)d_in[0];
    const int*   pconn = (const int*)d_in[1];
    const int*   lconn = (const int*)d_in[2];
    float* out = (float*)d_out;
    float* ws  = (float*)d_ws;

    const int nbins = NIMG * BINS;  // 264
    zero_ws_kernel<<<(nbins + 255) / 256, 256, 0, stream>>>(ws, nbins);

    dim3 grid(256, NIMG);
    accum_kernel<<<grid, 256, 0, stream>>>(pred, pconn, lconn, ws);

    finalize_kernel<<<1, 64, 0, stream>>>(ws, out);
}

// Round 2
// 111.786 us; speedup vs baseline: 1.3223x; 1.3223x over previous
//
#include <hip/hip_runtime.h>

#define PP 10
#define LL 6
#define NIMG 4
#define HW (1024*1024)
#define BINS 66          // 60 inter bins (l*10+p) + 6 label-count bins (60+l)
#define BX 128           // blocks per image
#define TPB 256
#define ITERS (HW / 4 / (BX * TPB))   // = 8, exact

__global__ __launch_bounds__(TPB) void accum_kernel(
    const float* __restrict__ pred,
    const int*   __restrict__ pconn,
    const int*   __restrict__ lconn,
    float*       __restrict__ ws)
{
    // Per-thread privatized bins: sb[bin*256 + tid]. Bank = tid % 32 ->
    // 2 lanes/bank for a wave64 access = conflict-free (m136).
    __shared__ float sb[BINS * TPB];

    const int tid = threadIdx.x;
    const int img = blockIdx.y;
    const size_t base = (size_t)img * HW;

    // zero LDS (float4 stores, 17 per thread)
    {
        float4* sb4 = (float4*)sb;
        const int n4 = BINS * TPB / 4;
        for (int i = tid; i < n4; i += TPB) sb4[i] = make_float4(0.f, 0.f, 0.f, 0.f);
    }
    __syncthreads();

    const float4* __restrict__ p4  = (const float4*)(pred  + base);
    const int4*   __restrict__ pc4 = (const int4*)(pconn + base);
    const int4*   __restrict__ lc4 = (const int4*)(lconn + base);

    const int v0 = blockIdx.x * TPB + tid;
    const int stride = BX * TPB;  // 32768 vec4s

    // Hoist ALL loads first: 24 outstanding 16B loads/wave -> latency hidden.
    float4 p[ITERS]; int4 pc[ITERS], lc[ITERS];
#pragma unroll
    for (int i = 0; i < ITERS; ++i) {
        const int v = v0 + i * stride;
        p[i]  = p4[v];
        pc[i] = pc4[v];
        lc[i] = lc4[v];
    }

    // Private accumulation: no atomics, in-order DS pipe handles RAW.
#pragma unroll
    for (int i = 0; i < ITERS; ++i) {
        sb[(lc[i].x * PP + pc[i].x) * TPB + tid] += p[i].x;
        sb[(60 + lc[i].x) * TPB + tid] += 1.0f;
        sb[(lc[i].y * PP + pc[i].y) * TPB + tid] += p[i].y;
        sb[(60 + lc[i].y) * TPB + tid] += 1.0f;
        sb[(lc[i].z * PP + pc[i].z) * TPB + tid] += p[i].z;
        sb[(60 + lc[i].z) * TPB + tid] += 1.0f;
        sb[(lc[i].w * PP + pc[i].w) * TPB + tid] += p[i].w;
        sb[(60 + lc[i].w) * TPB + tid] += 1.0f;
    }
    __syncthreads();

    // Block reduction: thread t handles (bin = t>>2, quarter = t&3).
    // Rotated float4 reads break the same-bank stride (8-way worst case).
    {
        const int b = tid >> 2, q = tid & 3;
        const float* col = sb + b * TPB + 64 * q;
        float s = 0.0f;
#pragma unroll
        for (int i = 0; i < 16; ++i) {
            const int ii = ((i + tid) & 15) * 4;
            const float4 t4 = *(const float4*)(col + ii);
            s += t4.x + t4.y + t4.z + t4.w;
        }
        s += __shfl_down(s, 1, 64);
        s += __shfl_down(s, 2, 64);
        if (q == 0) atomicAdd(&ws[img * BINS + b], s);
    }
    // Bins 64, 65 (counts for l=4,5): wave 0 does a second small fold.
    if (tid < 64) {
        const int b = 64 + ((tid >> 2) & 1), q = tid & 3;
        const float* col = sb + b * TPB + 64 * q;
        float s = 0.0f;
#pragma unroll
        for (int i = 0; i < 16; ++i) {
            const int ii = ((i + tid) & 15) * 4;
            const float4 t4 = *(const float4*)(col + ii);
            s += t4.x + t4.y + t4.z + t4.w;
        }
        s += __shfl_down(s, 1, 64);
        s += __shfl_down(s, 2, 64);
        if (tid < 8 && q == 0) atomicAdd(&ws[img * BINS + b], s);
    }
}

__global__ void finalize_kernel(const float* __restrict__ ws, float* __restrict__ out) {
    if (threadIdx.x != 0 || blockIdx.x != 0) return;
    float total = 0.0f;
    for (int img = 0; img < NIMG; ++img) {
        const float* b = ws + img * BINS;
        float inter[LL][PP];
        float pred_area[PP];
        float label_area[LL];
        for (int p = 0; p < PP; ++p) pred_area[p] = 0.0f;
        for (int l = 0; l < LL; ++l) {
            label_area[l] = b[60 + l];
            for (int p = 0; p < PP; ++p) {
                inter[l][p] = b[l * PP + p];
                pred_area[p] += inter[l][p];
            }
        }
        float ious[LL][PP];
        for (int l = 1; l < LL; ++l) {
            for (int p = 1; p < PP; ++p) {
                float in = inter[l][p];
                float un = label_area[l] + pred_area[p] - in;
                float iou;
                if (in == 0.0f)      iou = 0.0f;
                else if (un == 0.0f) iou = 1.0f;
                else                 iou = in / un;
                ious[l][p] = iou;
            }
        }
        float pair_conn_sum = 0.0f;
        for (int l = 1; l < LL; ++l) {
            float pc = 0.0f; int pn = 0;
            for (int p = 1; p < PP; ++p) {
                pc += ious[l][p];
                pn += (ious[l][p] != 0.0f) ? 1 : 0;
            }
            if (pn > 0) pair_conn_sum += pc / (float)pn;
        }
        int lone = 0;
        for (int p = 1; p < PP; ++p) {
            float cs = 0.0f;
            for (int l = 1; l < LL; ++l) cs += ious[l][p];
            lone += (cs == 0.0f) ? 1 : 0;
        }
        float img_conn = pair_conn_sum / (5.0f + (float)lone);
        total += 1.0f - img_conn;
    }
    out[0] = total / (float)NIMG;
}

extern "C" void kernel_launch(void* const* d_in, const int* in_sizes, int n_in,
                              void* d_out, int out_size, void* d_ws, size_t ws_size,
                              hipStream_t stream) {
    const float* pred  = (const float*)d_in[0];
    const int*   pconn = (const int*)d_in[1];
    const int*   lconn = (const int*)d_in[2];
    float* out = (float*)d_out;
    float* ws  = (float*)d_ws;

    hipMemsetAsync(ws, 0, NIMG * BINS * sizeof(float), stream);

    dim3 grid(BX, NIMG);
    accum_kernel<<<grid, TPB, 0, stream>>>(pred, pconn, lconn, ws);

    finalize_kernel<<<1, 64, 0, stream>>>(ws, out);
}